// Round 6
// baseline (1713.704 us; speedup 1.0000x reference)
//
#include <hip/hip_runtime.h>

#define EMBED 4096
#define NHEADS 32
#define HDIM 128
#define MAXLEN 4096
#define BATCH 8
#define NSPLIT 32
#define GRID 1024
#define NKVITEMS 512                 // 2 projections x 256 row-tiles (16 rows each)
#define NATTN (256 * NSPLIT)         // 8192 attention chunk items
#define NITEMS (NKVITEMS + NATTN)

typedef float __attribute__((ext_vector_type(4))) f32x4;

// ---------------- grid-wide barrier (device-scope, co-resident grid) ----------
__device__ __forceinline__ void gbar(unsigned* bar, unsigned target) {
    __syncthreads();
    __threadfence();
    if (threadIdx.x == 0) {
        __hip_atomic_fetch_add(bar, 1u, __ATOMIC_ACQ_REL, __HIP_MEMORY_SCOPE_AGENT);
        while (__hip_atomic_load(bar, __ATOMIC_ACQUIRE, __HIP_MEMORY_SCOPE_AGENT) < target)
            __builtin_amdgcn_s_sleep(4);
    }
    __syncthreads();
    __threadfence();
}

// ---------------- GEMM body: out[m][n..n+RPW) for m in [0,8) ------------------
// NOTE: n must already include the per-wave offset (wave*RPW).
template<int RPW>
__device__ __forceinline__ void gemm8_body(const float* __restrict__ X,
                                           const float* __restrict__ W,
                                           const float* __restrict__ bias,
                                           float* __restrict__ out, int n)
{
    const int lane = threadIdx.x & 63;

    float acc[RPW][8];
    #pragma unroll
    for (int j = 0; j < RPW; ++j)
        #pragma unroll
        for (int m = 0; m < 8; ++m) acc[j][m] = 0.f;

    const float* wb = W + (size_t)n * EMBED;

    #pragma unroll 1
    for (int i = 0; i < 16; ++i) {
        int c = i * 256 + lane * 4;
        f32x4 wv[RPW];
        #pragma unroll
        for (int j = 0; j < RPW; ++j)
            wv[j] = *(const f32x4*)(wb + (size_t)j * EMBED + c);
        #pragma unroll
        for (int m = 0; m < 8; ++m) {
            f32x4 xv = *(const f32x4*)(X + (size_t)m * EMBED + c);
            #pragma unroll
            for (int j = 0; j < RPW; ++j) {
                acc[j][m] += xv.x * wv[j].x + xv.y * wv[j].y
                           + xv.z * wv[j].z + xv.w * wv[j].w;
            }
        }
    }

    #pragma unroll
    for (int j = 0; j < RPW; ++j)
        #pragma unroll
        for (int m = 0; m < 8; ++m) {
            float v = acc[j][m];
            #pragma unroll
            for (int off = 32; off > 0; off >>= 1) v += __shfl_xor(v, off, 64);
            if (lane == 0) out[(size_t)m * EMBED + n + j] = v + bias[n + j];
        }
}

__global__ void init_ctrl(unsigned* ctrl) {
    if (threadIdx.x < 8) ctrl[threadIdx.x] = 0u;
}

__global__ __launch_bounds__(256, 4)
void fused_kernel(const float* __restrict__ x,
                  const float* __restrict__ kc, const float* __restrict__ vc,
                  const float* __restrict__ Wq, const float* __restrict__ bq,
                  const float* __restrict__ Wk, const float* __restrict__ bk,
                  const float* __restrict__ Wv, const float* __restrict__ bv,
                  const float* __restrict__ Wo, const float* __restrict__ bo,
                  const int* __restrict__ clp,
                  float* __restrict__ out,
                  float* __restrict__ ws_f, unsigned* __restrict__ ctrl)
{
    float* qkvq = ws_f;                                    // [8][4096]
    float* qkvk = qkvq + (size_t)BATCH * EMBED;            // [8][4096]
    float* qkvv = qkvk + (size_t)BATCH * EMBED;            // [8][4096]
    float* attnO = qkvv + (size_t)BATCH * EMBED;           // [8][4096]
    float* part_acc = attnO + (size_t)BATCH * EMBED;       // [256][NSPLIT][128]
    float* part_ms  = part_acc + (size_t)256 * NSPLIT * HDIM;  // [256][NSPLIT][2]
    unsigned* ctr  = ctrl;          // work-queue counter
    unsigned* bars = ctrl + 1;      // 3 barrier slots

    __shared__ float accs[8][HDIM];
    __shared__ float mls[8][2];
    __shared__ float sred[128];
    __shared__ int   sItem;

    const int cl  = *clp;                    // attention phase covers keys [0, cl)
    const int CH  = (cl + NSPLIT - 1) / NSPLIT;
    const int tid = threadIdx.x, lane = tid & 63, w = tid >> 6;
    const int half = lane >> 5, col4 = lane & 31;
    const int g = w * 2 + half;
    const int bid = blockIdx.x;
    const float scale = 0.08838834764831845f;   // 1/sqrt(128)

    // ================= phase 1: q projection (blocks 0..255) =================
    if (bid < 256)
        gemm8_body<4>(x, Wq, bq, qkvq, bid * 16 + w * 4);
    gbar(bars + 0, GRID);

    // ===== phase 2: dynamic queue: k/v projections + attention chunks ========
    for (;;) {
        if (tid == 0) sItem = (int)atomicAdd(ctr, 1u);
        __syncthreads();
        int item = sItem;
        if (item >= NITEMS) break;

        if (item < NKVITEMS) {
            int proj = item >> 8;                    // 0 -> K, 1 -> V
            int n0 = (item & 255) * 16 + w * 4;
            if (proj == 0) gemm8_body<4>(x, Wk, bk, qkvk, n0);
            else           gemm8_body<4>(x, Wv, bv, qkvv, n0);
        } else {
            int idx = item - NKVITEMS;
            int bh = idx >> 5;                       // /NSPLIT
            int sp = idx & (NSPLIT - 1);
            int b_ = bh >> 5, h = bh & 31;
            int tstart = sp * CH;
            int tend   = min(cl, tstart + CH);

            const float* q = qkvq + (size_t)b_ * EMBED + h * HDIM;
            const float* K = kc + (size_t)bh * MAXLEN * HDIM + col4 * 4;
            const float* V = vc + (size_t)bh * MAXLEN * HDIM + col4 * 4;

            f32x4 qv = *(const f32x4*)(q + col4 * 4);
            qv *= scale;

            float m = -3.0e38f, l = 0.f;
            f32x4 acc = {0.f, 0.f, 0.f, 0.f};

            for (int base = tstart + g; base < tend; base += 32) {
                f32x4 kv[4], vv[4];
                #pragma unroll
                for (int u = 0; u < 4; ++u) {
                    int t = base + u * 8;
                    if (t < tend) {
                        kv[u] = *(const f32x4*)(K + (size_t)t * HDIM);
                        vv[u] = *(const f32x4*)(V + (size_t)t * HDIM);
                    }
                }
                #pragma unroll
                for (int u = 0; u < 4; ++u) {
                    int t = base + u * 8;
                    if (t < tend) {
                        float s = qv.x * kv[u].x + qv.y * kv[u].y
                                + qv.z * kv[u].z + qv.w * kv[u].w;
                        #pragma unroll
                        for (int off = 16; off > 0; off >>= 1)
                            s += __shfl_xor(s, off, 64);
                        float mn   = fmaxf(m, s);
                        float corr = __expf(m - mn);
                        float p    = __expf(s - mn);
                        l = l * corr + p;
                        acc.x = fmaf(acc.x, corr, p * vv[u].x);
                        acc.y = fmaf(acc.y, corr, p * vv[u].y);
                        acc.z = fmaf(acc.z, corr, p * vv[u].z);
                        acc.w = fmaf(acc.w, corr, p * vv[u].w);
                        m = mn;
                    }
                }
            }

            if (col4 == 0) { mls[g][0] = m; mls[g][1] = l; }
            *(f32x4*)(&accs[g][col4 * 4]) = acc;
            __syncthreads();

            const size_t pidx = (size_t)bh * NSPLIT + sp;
            if (tid < HDIM) {
                float M = mls[0][0];
                #pragma unroll
                for (int i = 1; i < 8; ++i) M = fmaxf(M, mls[i][0]);
                float L = 0.f, o = 0.f;
                #pragma unroll
                for (int i = 0; i < 8; ++i) {
                    float wgt = __expf(mls[i][0] - M);
                    L += mls[i][1] * wgt;
                    o += accs[i][tid] * wgt;
                }
                part_acc[pidx * HDIM + tid] = o;
                if (tid == 0) {
                    part_ms[pidx * 2]     = M;
                    part_ms[pidx * 2 + 1] = L;
                }
            }
        }
        __syncthreads();   // protect sItem / accs reuse
    }
    gbar(bars + 1, GRID);

    // ======== phase 3: combine splits + fold in new key (blocks 0..255) ======
    if (bid < 256) {
        const int bh = bid;
        const int b_ = bh >> 5, h = bh & 31;
        const float* q    = qkvq + (size_t)b_ * EMBED + h * HDIM;
        const float* knew = qkvk + (size_t)b_ * EMBED + h * HDIM;
        const float* vnew = qkvv + (size_t)b_ * EMBED + h * HDIM;

        if (tid < HDIM) sred[tid] = q[tid] * knew[tid];
        __syncthreads();
        for (int s = 64; s > 0; s >>= 1) {
            if (tid < s) sred[tid] += sred[tid + s];
            __syncthreads();
        }
        float s_new = sred[0] * scale;

        if (tid < HDIM) {
            float M = s_new;
            #pragma unroll 1
            for (int sp = 0; sp < NSPLIT; ++sp)
                M = fmaxf(M, part_ms[((size_t)bh * NSPLIT + sp) * 2]);
            float wn = __expf(s_new - M);
            float L = wn;
            float o = wn * vnew[tid];
            #pragma unroll 1
            for (int sp = 0; sp < NSPLIT; ++sp) {
                float wgt = __expf(part_ms[((size_t)bh * NSPLIT + sp) * 2] - M);
                L += part_ms[((size_t)bh * NSPLIT + sp) * 2 + 1] * wgt;
                o += part_acc[((size_t)bh * NSPLIT + sp) * HDIM + tid] * wgt;
            }
            attnO[(size_t)b_ * EMBED + h * HDIM + tid] = o / L;
        }
    }
    gbar(bars + 2, GRID);

    // ================= phase 4: output projection (blocks 0..255) ============
    if (bid < 256)
        gemm8_body<4>(attnO, Wo, bo, out, bid * 16 + w * 4);
}

extern "C" void kernel_launch(void* const* d_in, const int* in_sizes, int n_in,
                              void* d_out, int out_size, void* d_ws, size_t ws_size,
                              hipStream_t stream) {
    const float* x  = (const float*)d_in[0];
    const float* kc = (const float*)d_in[1];
    const float* vc = (const float*)d_in[2];
    const float* Wq = (const float*)d_in[3];
    const float* bq = (const float*)d_in[4];
    const float* Wk = (const float*)d_in[5];
    const float* bk = (const float*)d_in[6];
    const float* Wv = (const float*)d_in[7];
    const float* bv = (const float*)d_in[8];
    const float* Wo = (const float*)d_in[9];
    const float* bo = (const float*)d_in[10];
    const int* clp  = (const int*)d_in[11];

    float* out  = (float*)d_out;
    float* ws_f = (float*)d_ws;
    // float region: 4*B*E + 256*NSPLIT*128 + 256*NSPLIT*2 floats ≈ 4.8 MB
    size_t fcount = (size_t)4 * BATCH * EMBED
                  + (size_t)256 * NSPLIT * HDIM + (size_t)256 * NSPLIT * 2;
    unsigned* ctrl = (unsigned*)(ws_f + fcount);

    hipLaunchKernelGGL(init_ctrl, dim3(1), dim3(64), 0, stream, ctrl);
    hipLaunchKernelGGL(fused_kernel, dim3(GRID), dim3(256), 0, stream,
                       x, kc, vc, Wq, bq, Wk, bk, Wv, bv, Wo, bo, clp,
                       out, ws_f, ctrl);
}

// Round 7
// 282.540 us; speedup vs baseline: 6.0654x; 6.0654x over previous
//
#include <hip/hip_runtime.h>

#define EMBED 4096
#define NHEADS 32
#define HDIM 128
#define MAXLEN 4096
#define BATCH 8
#define NSPLIT 16
#define NKVBLK 512                    // 2 projections x 256 row-tiles

typedef float __attribute__((ext_vector_type(4))) f32x4;

// ---------------- GEMM body: out[m][n..n+RPW) for m in [0,8) ------------------
// NOTE: n must already include the per-wave offset (wave*RPW).
template<int RPW>
__device__ __forceinline__ void gemm8_body(const float* __restrict__ X,
                                           const float* __restrict__ W,
                                           const float* __restrict__ bias,
                                           float* __restrict__ out, int n)
{
    const int lane = threadIdx.x & 63;

    float acc[RPW][8];
    #pragma unroll
    for (int j = 0; j < RPW; ++j)
        #pragma unroll
        for (int m = 0; m < 8; ++m) acc[j][m] = 0.f;

    const float* wb = W + (size_t)n * EMBED;

    #pragma unroll 1
    for (int i = 0; i < 16; ++i) {
        int c = i * 256 + lane * 4;
        f32x4 wv[RPW];
        #pragma unroll
        for (int j = 0; j < RPW; ++j)
            wv[j] = *(const f32x4*)(wb + (size_t)j * EMBED + c);
        #pragma unroll
        for (int m = 0; m < 8; ++m) {
            f32x4 xv = *(const f32x4*)(X + (size_t)m * EMBED + c);
            #pragma unroll
            for (int j = 0; j < RPW; ++j) {
                acc[j][m] += xv.x * wv[j].x + xv.y * wv[j].y
                           + xv.z * wv[j].z + xv.w * wv[j].w;
            }
        }
    }

    #pragma unroll
    for (int j = 0; j < RPW; ++j)
        #pragma unroll
        for (int m = 0; m < 8; ++m) {
            float v = acc[j][m];
            #pragma unroll
            for (int off = 32; off > 0; off >>= 1) v += __shfl_xor(v, off, 64);
            if (lane == 0) out[(size_t)m * EMBED + n + j] = v + bias[n + j];
        }
}

// ---------------- kernel A: q projection -------------------------------------
__global__ __launch_bounds__(256)
void qproj_kernel(const float* __restrict__ x,
                  const float* __restrict__ Wq, const float* __restrict__ bq,
                  float* __restrict__ qkvq)
{
    const int w = threadIdx.x >> 6;
    gemm8_body<4>(x, Wq, bq, qkvq, blockIdx.x * 16 + w * 4);
}

// ------ kernel B: hybrid — kv projections + attention over keys [0, cl) ------
__global__ __launch_bounds__(256)
void mid_kernel(const float* __restrict__ x,
                const float* __restrict__ kc, const float* __restrict__ vc,
                const float* __restrict__ Wk, const float* __restrict__ bk,
                const float* __restrict__ Wv, const float* __restrict__ bv,
                const float* __restrict__ qkvq,
                float* __restrict__ qkvk, float* __restrict__ qkvv,
                const int* __restrict__ clp,
                float* __restrict__ part_acc,   // [256][NSPLIT][128]
                float* __restrict__ part_ms)    // [256][NSPLIT][2]
{
    const int bid = blockIdx.x;
    const int tid = threadIdx.x, w = tid >> 6, lane = tid & 63;

    if (bid < NKVBLK) {
        int proj = bid >> 8;
        int n0 = (bid & 255) * 16 + w * 4;
        if (proj == 0) gemm8_body<4>(x, Wk, bk, qkvk, n0);
        else           gemm8_body<4>(x, Wv, bv, qkvv, n0);
        return;
    }

    __shared__ float accs[8][HDIM];
    __shared__ float mls[8][2];

    const int cl = *clp;                       // keys [0, cl)
    const int CH = (cl + NSPLIT - 1) / NSPLIT;

    const int idx = bid - NKVBLK;
    const int bh = idx & 255;
    const int sp = idx >> 8;
    const int b_ = bh >> 5, h = bh & 31;
    const int half = lane >> 5, col4 = lane & 31;
    const int g = w * 2 + half;

    const int tstart = sp * CH;
    const int tend   = min(cl, tstart + CH);

    const float* q = qkvq + (size_t)b_ * EMBED + h * HDIM;
    const float* K = kc + (size_t)bh * MAXLEN * HDIM + col4 * 4;
    const float* V = vc + (size_t)bh * MAXLEN * HDIM + col4 * 4;

    const float scale = 0.08838834764831845f;   // 1/sqrt(128)
    f32x4 qv = *(const f32x4*)(q + col4 * 4);
    qv *= scale;

    float m = -3.0e38f, l = 0.f;
    f32x4 acc = {0.f, 0.f, 0.f, 0.f};

    for (int base = tstart + g; base < tend; base += 32) {
        f32x4 kv[4], vv[4];
        #pragma unroll
        for (int u = 0; u < 4; ++u) {
            int t = base + u * 8;
            if (t < tend) {
                kv[u] = *(const f32x4*)(K + (size_t)t * HDIM);
                vv[u] = *(const f32x4*)(V + (size_t)t * HDIM);
            }
        }
        #pragma unroll
        for (int u = 0; u < 4; ++u) {
            int t = base + u * 8;
            if (t < tend) {
                float s = qv.x * kv[u].x + qv.y * kv[u].y
                        + qv.z * kv[u].z + qv.w * kv[u].w;
                #pragma unroll
                for (int off = 16; off > 0; off >>= 1)
                    s += __shfl_xor(s, off, 64);
                float mn   = fmaxf(m, s);
                float corr = __expf(m - mn);
                float p    = __expf(s - mn);
                l = l * corr + p;
                acc.x = fmaf(acc.x, corr, p * vv[u].x);
                acc.y = fmaf(acc.y, corr, p * vv[u].y);
                acc.z = fmaf(acc.z, corr, p * vv[u].z);
                acc.w = fmaf(acc.w, corr, p * vv[u].w);
                m = mn;
            }
        }
    }

    if (col4 == 0) { mls[g][0] = m; mls[g][1] = l; }
    *(f32x4*)(&accs[g][col4 * 4]) = acc;
    __syncthreads();

    const size_t pidx = (size_t)bh * NSPLIT + sp;
    if (tid < HDIM) {
        float M = mls[0][0];
        #pragma unroll
        for (int i = 1; i < 8; ++i) M = fmaxf(M, mls[i][0]);
        float L = 0.f, o = 0.f;
        #pragma unroll
        for (int i = 0; i < 8; ++i) {
            float wgt = __expf(mls[i][0] - M);
            L += mls[i][1] * wgt;
            o += accs[i][tid] * wgt;
        }
        part_acc[pidx * HDIM + tid] = o;
        if (tid == 0) {
            part_ms[pidx * 2]     = M;
            part_ms[pidx * 2 + 1] = L;
        }
    }
}

// ------- kernel C: combine splits + fold in the new key ----------------------
__global__ __launch_bounds__(128)
void combine_kernel(const float* __restrict__ qkvq,
                    const float* __restrict__ qkvk, const float* __restrict__ qkvv,
                    const float* __restrict__ part_acc,
                    const float* __restrict__ part_ms,
                    float* __restrict__ attnO)
{
    __shared__ float sred[2];
    const int bh = blockIdx.x;
    const int b_ = bh >> 5, h = bh & 31;
    const int d = threadIdx.x, lane = d & 63, w = d >> 6;

    const float* q    = qkvq + (size_t)b_ * EMBED + h * HDIM;
    const float* knew = qkvk + (size_t)b_ * EMBED + h * HDIM;
    const float* vnew = qkvv + (size_t)b_ * EMBED + h * HDIM;

    float prod = q[d] * knew[d];
    #pragma unroll
    for (int off = 32; off > 0; off >>= 1) prod += __shfl_xor(prod, off, 64);
    if (lane == 0) sred[w] = prod;
    __syncthreads();
    const float s_new = (sred[0] + sred[1]) * 0.08838834764831845f;

    float M = s_new;
    float ms[NSPLIT], ls[NSPLIT];
    #pragma unroll
    for (int sp = 0; sp < NSPLIT; ++sp) {
        ms[sp] = part_ms[((size_t)bh * NSPLIT + sp) * 2];
        ls[sp] = part_ms[((size_t)bh * NSPLIT + sp) * 2 + 1];
        M = fmaxf(M, ms[sp]);
    }
    float wn = __expf(s_new - M);
    float L = wn;
    float o = wn * vnew[d];
    #pragma unroll
    for (int sp = 0; sp < NSPLIT; ++sp) {
        float wgt = __expf(ms[sp] - M);
        L += ls[sp] * wgt;
        o += part_acc[((size_t)bh * NSPLIT + sp) * HDIM + d] * wgt;
    }
    attnO[(size_t)b_ * EMBED + h * HDIM + d] = o / L;
}

// ---------------- kernel D: output projection --------------------------------
__global__ __launch_bounds__(256)
void out_kernel(const float* __restrict__ attnO,
                const float* __restrict__ Wo, const float* __restrict__ bo,
                float* __restrict__ out)
{
    const int w = threadIdx.x >> 6;
    gemm8_body<2>(attnO, Wo, bo, out, blockIdx.x * 8 + w * 2);
}

extern "C" void kernel_launch(void* const* d_in, const int* in_sizes, int n_in,
                              void* d_out, int out_size, void* d_ws, size_t ws_size,
                              hipStream_t stream) {
    const float* x  = (const float*)d_in[0];
    const float* kc = (const float*)d_in[1];
    const float* vc = (const float*)d_in[2];
    const float* Wq = (const float*)d_in[3];
    const float* bq = (const float*)d_in[4];
    const float* Wk = (const float*)d_in[5];
    const float* bk = (const float*)d_in[6];
    const float* Wv = (const float*)d_in[7];
    const float* bv = (const float*)d_in[8];
    const float* Wo = (const float*)d_in[9];
    const float* bo = (const float*)d_in[10];
    const int* clp  = (const int*)d_in[11];

    float* out  = (float*)d_out;
    float* qkvq = (float*)d_ws;                               // [8][4096]
    float* qkvk = qkvq + (size_t)BATCH * EMBED;               // [8][4096]
    float* qkvv = qkvk + (size_t)BATCH * EMBED;               // [8][4096]
    float* attnO = qkvv + (size_t)BATCH * EMBED;              // [8][4096]
    float* part_acc = attnO + (size_t)BATCH * EMBED;          // [256][NSPLIT][128]
    float* part_ms  = part_acc + (size_t)256 * NSPLIT * HDIM; // [256][NSPLIT][2]

    hipLaunchKernelGGL(qproj_kernel, dim3(256), dim3(256), 0, stream,
                       x, Wq, bq, qkvq);
    hipLaunchKernelGGL(mid_kernel, dim3(NKVBLK + 256 * NSPLIT), dim3(256), 0, stream,
                       x, kc, vc, Wk, bk, Wv, bv, qkvq, qkvk, qkvv, clp,
                       part_acc, part_ms);
    hipLaunchKernelGGL(combine_kernel, dim3(256), dim3(128), 0, stream,
                       qkvq, qkvk, qkvv, part_acc, part_ms, attnO);
    hipLaunchKernelGGL(out_kernel, dim3(512), dim3(256), 0, stream,
                       attnO, Wo, bo, out);
}

// Round 8
// 282.092 us; speedup vs baseline: 6.0750x; 1.0016x over previous
//
#include <hip/hip_runtime.h>

#define EMBED 4096
#define NHEADS 32
#define HDIM 128
#define MAXLEN 4096
#define BATCH 8
#define NSPLIT 16

typedef float __attribute__((ext_vector_type(4))) f32x4;

// ---------------- GEMM body: out[m][n..n+RPW) for m in [0,8) ------------------
// NOTE: n must already include the per-wave offset (wave*RPW).
template<int RPW>
__device__ __forceinline__ void gemm8_body(const float* __restrict__ X,
                                           const float* __restrict__ W,
                                           const float* __restrict__ bias,
                                           float* __restrict__ out, int n)
{
    const int lane = threadIdx.x & 63;

    float acc[RPW][8];
    #pragma unroll
    for (int j = 0; j < RPW; ++j)
        #pragma unroll
        for (int m = 0; m < 8; ++m) acc[j][m] = 0.f;

    const float* wb = W + (size_t)n * EMBED;

    #pragma unroll 1
    for (int i = 0; i < 16; ++i) {
        int c = i * 256 + lane * 4;
        f32x4 wv[RPW];
        #pragma unroll
        for (int j = 0; j < RPW; ++j)
            wv[j] = *(const f32x4*)(wb + (size_t)j * EMBED + c);
        #pragma unroll
        for (int m = 0; m < 8; ++m) {
            f32x4 xv = *(const f32x4*)(X + (size_t)m * EMBED + c);
            #pragma unroll
            for (int j = 0; j < RPW; ++j) {
                acc[j][m] += xv.x * wv[j].x + xv.y * wv[j].y
                           + xv.z * wv[j].z + xv.w * wv[j].w;
            }
        }
    }

    #pragma unroll
    for (int j = 0; j < RPW; ++j)
        #pragma unroll
        for (int m = 0; m < 8; ++m) {
            float v = acc[j][m];
            #pragma unroll
            for (int off = 32; off > 0; off >>= 1) v += __shfl_xor(v, off, 64);
            if (lane == 0) out[(size_t)m * EMBED + n + j] = v + bias[n + j];
        }
}

// -------- kernel A: all three projections (q,k,v), RPW=2, 1536 blocks --------
__global__ __launch_bounds__(256)
void qkv_kernel(const float* __restrict__ x,
                const float* __restrict__ Wq, const float* __restrict__ bq,
                const float* __restrict__ Wk, const float* __restrict__ bk,
                const float* __restrict__ Wv, const float* __restrict__ bv,
                float* __restrict__ qkv /* [3][8][4096] */)
{
    const int w = threadIdx.x >> 6;
    int ng = blockIdx.x * 8 + w * 2;         // global row among 3*4096
    int proj = ng >> 12;
    int n = ng & 4095;
    const float* W = proj == 0 ? Wq : (proj == 1 ? Wk : Wv);
    const float* b = proj == 0 ? bq : (proj == 1 ? bk : bv);
    float* out = qkv + (size_t)proj * (BATCH * EMBED);
    gemm8_body<2>(x, W, b, out, n);
}

// -------- kernel B: flash-decode attention over keys [0, cl), branch-free ----
__global__ __launch_bounds__(256)
void attn_partial(const float* __restrict__ qkv,
                  const float* __restrict__ kc, const float* __restrict__ vc,
                  const int* __restrict__ clp,
                  float* __restrict__ part_acc,   // [256][NSPLIT][128]
                  float* __restrict__ part_ms)    // [256][NSPLIT][2]
{
    __shared__ float accs[8][HDIM];
    __shared__ float mls[8][2];

    const int cl = *clp;                       // keys [0, cl)
    const int CH = (cl + NSPLIT - 1) / NSPLIT;

    const int bh = blockIdx.x & 255;
    const int sp = blockIdx.x >> 8;
    const int b_ = bh >> 5, h = bh & 31;
    const int tid = threadIdx.x, w = tid >> 6, lane = tid & 63;
    const int half = lane >> 5, col4 = lane & 31;
    const int g = w * 2 + half;

    const int tstart = sp * CH;
    const int tend   = min(cl, tstart + CH);

    const float* q = qkv + (size_t)b_ * EMBED + h * HDIM;
    const float* K = kc + (size_t)bh * MAXLEN * HDIM + col4 * 4;
    const float* V = vc + (size_t)bh * MAXLEN * HDIM + col4 * 4;

    const float scale = 0.08838834764831845f;   // 1/sqrt(128)
    f32x4 qv = *(const f32x4*)(q + col4 * 4);
    qv *= scale;

    float m = -3.0e38f, l = 0.f;
    f32x4 acc = {0.f, 0.f, 0.f, 0.f};

    for (int base = tstart + g; base < tend; base += 32) {
        f32x4 kv[4], vv[4];
        #pragma unroll
        for (int u = 0; u < 4; ++u) {
            int t = base + u * 8;
            if (t < tend) {
                kv[u] = *(const f32x4*)(K + (size_t)t * HDIM);
                vv[u] = *(const f32x4*)(V + (size_t)t * HDIM);
            }
        }
        #pragma unroll
        for (int u = 0; u < 4; ++u) {
            int t = base + u * 8;
            if (t < tend) {
                float s = qv.x * kv[u].x + qv.y * kv[u].y
                        + qv.z * kv[u].z + qv.w * kv[u].w;
                #pragma unroll
                for (int off = 16; off > 0; off >>= 1)
                    s += __shfl_xor(s, off, 64);
                float mn   = fmaxf(m, s);
                float corr = __expf(m - mn);
                float p    = __expf(s - mn);
                l = l * corr + p;
                acc.x = fmaf(acc.x, corr, p * vv[u].x);
                acc.y = fmaf(acc.y, corr, p * vv[u].y);
                acc.z = fmaf(acc.z, corr, p * vv[u].z);
                acc.w = fmaf(acc.w, corr, p * vv[u].w);
                m = mn;
            }
        }
    }

    if (col4 == 0) { mls[g][0] = m; mls[g][1] = l; }
    *(f32x4*)(&accs[g][col4 * 4]) = acc;
    __syncthreads();

    const size_t pidx = (size_t)bh * NSPLIT + sp;
    if (tid < HDIM) {
        float M = mls[0][0];
        #pragma unroll
        for (int i = 1; i < 8; ++i) M = fmaxf(M, mls[i][0]);
        float L = 0.f, o = 0.f;
        #pragma unroll
        for (int i = 0; i < 8; ++i) {
            float wgt = __expf(mls[i][0] - M);
            L += mls[i][1] * wgt;
            o += accs[i][tid] * wgt;
        }
        part_acc[pidx * HDIM + tid] = o;
        if (tid == 0) {
            part_ms[pidx * 2]     = M;
            part_ms[pidx * 2 + 1] = L;
        }
    }
}

// ------- kernel C: combine splits + fold in the new key ----------------------
__global__ __launch_bounds__(128)
void combine_kernel(const float* __restrict__ qkv,
                    const float* __restrict__ part_acc,
                    const float* __restrict__ part_ms,
                    float* __restrict__ attnO)
{
    __shared__ float sred[2];
    const int bh = blockIdx.x;
    const int b_ = bh >> 5, h = bh & 31;
    const int d = threadIdx.x, lane = d & 63, w = d >> 6;

    const float* q    = qkv + (size_t)b_ * EMBED + h * HDIM;
    const float* knew = qkv + (size_t)BATCH * EMBED     + (size_t)b_ * EMBED + h * HDIM;
    const float* vnew = qkv + (size_t)2 * BATCH * EMBED + (size_t)b_ * EMBED + h * HDIM;

    float prod = q[d] * knew[d];
    #pragma unroll
    for (int off = 32; off > 0; off >>= 1) prod += __shfl_xor(prod, off, 64);
    if (lane == 0) sred[w] = prod;
    __syncthreads();
    const float s_new = (sred[0] + sred[1]) * 0.08838834764831845f;

    float M = s_new;
    float ms[NSPLIT], ls[NSPLIT];
    #pragma unroll
    for (int sp = 0; sp < NSPLIT; ++sp) {
        ms[sp] = part_ms[((size_t)bh * NSPLIT + sp) * 2];
        ls[sp] = part_ms[((size_t)bh * NSPLIT + sp) * 2 + 1];
        M = fmaxf(M, ms[sp]);
    }
    float wn = __expf(s_new - M);
    float L = wn;
    float o = wn * vnew[d];
    #pragma unroll
    for (int sp = 0; sp < NSPLIT; ++sp) {
        float wgt = __expf(ms[sp] - M);
        L += ls[sp] * wgt;
        o += part_acc[((size_t)bh * NSPLIT + sp) * HDIM + d] * wgt;
    }
    attnO[(size_t)b_ * EMBED + h * HDIM + d] = o / L;
}

// ---------------- kernel D: output projection --------------------------------
__global__ __launch_bounds__(256)
void out_kernel(const float* __restrict__ attnO,
                const float* __restrict__ Wo, const float* __restrict__ bo,
                float* __restrict__ out)
{
    const int w = threadIdx.x >> 6;
    gemm8_body<2>(attnO, Wo, bo, out, blockIdx.x * 8 + w * 2);
}

extern "C" void kernel_launch(void* const* d_in, const int* in_sizes, int n_in,
                              void* d_out, int out_size, void* d_ws, size_t ws_size,
                              hipStream_t stream) {
    const float* x  = (const float*)d_in[0];
    const float* kc = (const float*)d_in[1];
    const float* vc = (const float*)d_in[2];
    const float* Wq = (const float*)d_in[3];
    const float* bq = (const float*)d_in[4];
    const float* Wk = (const float*)d_in[5];
    const float* bk = (const float*)d_in[6];
    const float* Wv = (const float*)d_in[7];
    const float* bv = (const float*)d_in[8];
    const float* Wo = (const float*)d_in[9];
    const float* bo = (const float*)d_in[10];
    const int* clp  = (const int*)d_in[11];

    float* out  = (float*)d_out;
    float* qkv  = (float*)d_ws;                               // [3][8][4096]
    float* attnO = qkv + (size_t)3 * BATCH * EMBED;           // [8][4096]
    float* part_acc = attnO + (size_t)BATCH * EMBED;          // [256][NSPLIT][128]
    float* part_ms  = part_acc + (size_t)256 * NSPLIT * HDIM; // [256][NSPLIT][2]

    hipLaunchKernelGGL(qkv_kernel, dim3(1536), dim3(256), 0, stream,
                       x, Wq, bq, Wk, bk, Wv, bv, qkv);
    hipLaunchKernelGGL(attn_partial, dim3(256 * NSPLIT), dim3(256), 0, stream,
                       qkv, kc, vc, clp, part_acc, part_ms);
    hipLaunchKernelGGL(combine_kernel, dim3(256), dim3(128), 0, stream,
                       qkv, part_acc, part_ms, attnO);
    hipLaunchKernelGGL(out_kernel, dim3(512), dim3(256), 0, stream,
                       attnO, Wo, bo, out);
}

// Round 9
// 273.675 us; speedup vs baseline: 6.2618x; 1.0308x over previous
//
#include <hip/hip_runtime.h>

#define EMBED 4096
#define NHEADS 32
#define HDIM 128
#define MAXLEN 4096
#define BATCH 8
#define NSPLIT 16

typedef float __attribute__((ext_vector_type(4))) f32x4;

// ---------------- GEMM body: out[m][n..n+RPW) for m in [0,8) ------------------
// NOTE: n must already include the per-wave offset (wave*RPW).
template<int RPW>
__device__ __forceinline__ void gemm8_body(const float* __restrict__ X,
                                           const float* __restrict__ W,
                                           const float* __restrict__ bias,
                                           float* __restrict__ out, int n)
{
    const int lane = threadIdx.x & 63;

    float acc[RPW][8];
    #pragma unroll
    for (int j = 0; j < RPW; ++j)
        #pragma unroll
        for (int m = 0; m < 8; ++m) acc[j][m] = 0.f;

    const float* wb = W + (size_t)n * EMBED;

    #pragma unroll 1
    for (int i = 0; i < 16; ++i) {
        int c = i * 256 + lane * 4;
        f32x4 wv[RPW];
        #pragma unroll
        for (int j = 0; j < RPW; ++j)
            wv[j] = *(const f32x4*)(wb + (size_t)j * EMBED + c);
        #pragma unroll
        for (int m = 0; m < 8; ++m) {
            f32x4 xv = *(const f32x4*)(X + (size_t)m * EMBED + c);
            #pragma unroll
            for (int j = 0; j < RPW; ++j) {
                acc[j][m] += xv.x * wv[j].x + xv.y * wv[j].y
                           + xv.z * wv[j].z + xv.w * wv[j].w;
            }
        }
    }

    #pragma unroll
    for (int j = 0; j < RPW; ++j)
        #pragma unroll
        for (int m = 0; m < 8; ++m) {
            float v = acc[j][m];
            #pragma unroll
            for (int off = 32; off > 0; off >>= 1) v += __shfl_xor(v, off, 64);
            if (lane == 0) out[(size_t)m * EMBED + n + j] = v + bias[n + j];
        }
}

// -------- kernel A: all three projections (q,k,v), RPW=4, 768 blocks ---------
__global__ __launch_bounds__(256)
void qkv_kernel(const float* __restrict__ x,
                const float* __restrict__ Wq, const float* __restrict__ bq,
                const float* __restrict__ Wk, const float* __restrict__ bk,
                const float* __restrict__ Wv, const float* __restrict__ bv,
                float* __restrict__ qkv /* [3][8][4096] */)
{
    const int w = threadIdx.x >> 6;
    int ng = blockIdx.x * 16 + w * 4;        // global row among 3*4096
    int proj = ng >> 12;
    int n = ng & 4095;
    const float* W = proj == 0 ? Wq : (proj == 1 ? Wk : Wv);
    const float* b = proj == 0 ? bq : (proj == 1 ? bk : bv);
    float* out = qkv + (size_t)proj * (BATCH * EMBED);
    gemm8_body<4>(x, W, b, out, n);
}

// -------- kernel B: flash-decode attention over keys [0, cl), branch-free ----
__global__ __launch_bounds__(256)
void attn_partial(const float* __restrict__ qkv,
                  const float* __restrict__ kc, const float* __restrict__ vc,
                  const int* __restrict__ clp,
                  float* __restrict__ part_acc,   // [256][NSPLIT][128]
                  float* __restrict__ part_ms)    // [256][NSPLIT][2]
{
    __shared__ float accs[8][HDIM];
    __shared__ float mls[8][2];

    const int cl = *clp;                       // keys [0, cl)
    const int CH = (cl + NSPLIT - 1) / NSPLIT;

    const int bh = blockIdx.x & 255;
    const int sp = blockIdx.x >> 8;
    const int b_ = bh >> 5, h = bh & 31;
    const int tid = threadIdx.x, w = tid >> 6, lane = tid & 63;
    const int half = lane >> 5, col4 = lane & 31;
    const int g = w * 2 + half;

    const int tstart = sp * CH;
    const int tend   = min(cl, tstart + CH);

    const float* q = qkv + (size_t)b_ * EMBED + h * HDIM;
    const float* K = kc + (size_t)bh * MAXLEN * HDIM + col4 * 4;
    const float* V = vc + (size_t)bh * MAXLEN * HDIM + col4 * 4;

    const float scale = 0.08838834764831845f;   // 1/sqrt(128)
    f32x4 qv = *(const f32x4*)(q + col4 * 4);
    qv *= scale;

    float m = -3.0e38f, l = 0.f;
    f32x4 acc = {0.f, 0.f, 0.f, 0.f};

    for (int base = tstart + g; base < tend; base += 32) {
        f32x4 kv[4], vv[4];
        #pragma unroll
        for (int u = 0; u < 4; ++u) {
            int t = base + u * 8;
            if (t < tend) {
                kv[u] = *(const f32x4*)(K + (size_t)t * HDIM);
                vv[u] = *(const f32x4*)(V + (size_t)t * HDIM);
            }
        }
        #pragma unroll
        for (int u = 0; u < 4; ++u) {
            int t = base + u * 8;
            if (t < tend) {
                float s = qv.x * kv[u].x + qv.y * kv[u].y
                        + qv.z * kv[u].z + qv.w * kv[u].w;
                #pragma unroll
                for (int off = 16; off > 0; off >>= 1)
                    s += __shfl_xor(s, off, 64);
                float mn   = fmaxf(m, s);
                float corr = __expf(m - mn);
                float p    = __expf(s - mn);
                l = l * corr + p;
                acc.x = fmaf(acc.x, corr, p * vv[u].x);
                acc.y = fmaf(acc.y, corr, p * vv[u].y);
                acc.z = fmaf(acc.z, corr, p * vv[u].z);
                acc.w = fmaf(acc.w, corr, p * vv[u].w);
                m = mn;
            }
        }
    }

    if (col4 == 0) { mls[g][0] = m; mls[g][1] = l; }
    *(f32x4*)(&accs[g][col4 * 4]) = acc;
    __syncthreads();

    const size_t pidx = (size_t)bh * NSPLIT + sp;
    if (tid < HDIM) {
        float M = mls[0][0];
        #pragma unroll
        for (int i = 1; i < 8; ++i) M = fmaxf(M, mls[i][0]);
        float L = 0.f, o = 0.f;
        #pragma unroll
        for (int i = 0; i < 8; ++i) {
            float wgt = __expf(mls[i][0] - M);
            L += mls[i][1] * wgt;
            o += accs[i][tid] * wgt;
        }
        part_acc[pidx * HDIM + tid] = o;
        if (tid == 0) {
            part_ms[pidx * 2]     = M;
            part_ms[pidx * 2 + 1] = L;
        }
    }
}

// ------- kernel C: combine splits + fold in the new key ----------------------
__global__ __launch_bounds__(128)
void combine_kernel(const float* __restrict__ qkv,
                    const float* __restrict__ part_acc,
                    const float* __restrict__ part_ms,
                    float* __restrict__ attnO)
{
    __shared__ float sred[2];
    const int bh = blockIdx.x;
    const int b_ = bh >> 5, h = bh & 31;
    const int d = threadIdx.x, lane = d & 63, w = d >> 6;

    const float* q    = qkv + (size_t)b_ * EMBED + h * HDIM;
    const float* knew = qkv + (size_t)BATCH * EMBED     + (size_t)b_ * EMBED + h * HDIM;
    const float* vnew = qkv + (size_t)2 * BATCH * EMBED + (size_t)b_ * EMBED + h * HDIM;

    float prod = q[d] * knew[d];
    #pragma unroll
    for (int off = 32; off > 0; off >>= 1) prod += __shfl_xor(prod, off, 64);
    if (lane == 0) sred[w] = prod;
    __syncthreads();
    const float s_new = (sred[0] + sred[1]) * 0.08838834764831845f;

    float M = s_new;
    float ms[NSPLIT], ls[NSPLIT];
    #pragma unroll
    for (int sp = 0; sp < NSPLIT; ++sp) {
        ms[sp] = part_ms[((size_t)bh * NSPLIT + sp) * 2];
        ls[sp] = part_ms[((size_t)bh * NSPLIT + sp) * 2 + 1];
        M = fmaxf(M, ms[sp]);
    }
    float wn = __expf(s_new - M);
    float L = wn;
    float o = wn * vnew[d];
    #pragma unroll
    for (int sp = 0; sp < NSPLIT; ++sp) {
        float wgt = __expf(ms[sp] - M);
        L += ls[sp] * wgt;
        o += part_acc[((size_t)bh * NSPLIT + sp) * HDIM + d] * wgt;
    }
    attnO[(size_t)b_ * EMBED + h * HDIM + d] = o / L;
}

// ---------------- kernel D: output projection --------------------------------
__global__ __launch_bounds__(256)
void out_kernel(const float* __restrict__ attnO,
                const float* __restrict__ Wo, const float* __restrict__ bo,
                float* __restrict__ out)
{
    const int w = threadIdx.x >> 6;
    gemm8_body<2>(attnO, Wo, bo, out, blockIdx.x * 8 + w * 2);
}

extern "C" void kernel_launch(void* const* d_in, const int* in_sizes, int n_in,
                              void* d_out, int out_size, void* d_ws, size_t ws_size,
                              hipStream_t stream) {
    const float* x  = (const float*)d_in[0];
    const float* kc = (const float*)d_in[1];
    const float* vc = (const float*)d_in[2];
    const float* Wq = (const float*)d_in[3];
    const float* bq = (const float*)d_in[4];
    const float* Wk = (const float*)d_in[5];
    const float* bk = (const float*)d_in[6];
    const float* Wv = (const float*)d_in[7];
    const float* bv = (const float*)d_in[8];
    const float* Wo = (const float*)d_in[9];
    const float* bo = (const float*)d_in[10];
    const int* clp  = (const int*)d_in[11];

    float* out  = (float*)d_out;
    float* qkv  = (float*)d_ws;                               // [3][8][4096]
    float* attnO = qkv + (size_t)3 * BATCH * EMBED;           // [8][4096]
    float* part_acc = attnO + (size_t)BATCH * EMBED;          // [256][NSPLIT][128]
    float* part_ms  = part_acc + (size_t)256 * NSPLIT * HDIM; // [256][NSPLIT][2]

    hipLaunchKernelGGL(qkv_kernel, dim3(768), dim3(256), 0, stream,
                       x, Wq, bq, Wk, bk, Wv, bv, qkv);
    hipLaunchKernelGGL(attn_partial, dim3(256 * NSPLIT), dim3(256), 0, stream,
                       qkv, kc, vc, clp, part_acc, part_ms);
    hipLaunchKernelGGL(combine_kernel, dim3(256), dim3(128), 0, stream,
                       qkv, part_acc, part_ms, attnO);
    hipLaunchKernelGGL(out_kernel, dim3(512), dim3(256), 0, stream,
                       attnO, Wo, bo, out);
}